// Round 3
// baseline (2718.367 us; speedup 1.0000x reference)
//
#include <hip/hip_runtime.h>
#include <hip/hip_bf16.h>
#include <cstdint>

#define DEV __device__ __forceinline__

typedef __bf16 bf16x8 __attribute__((ext_vector_type(8)));
typedef float f32x4 __attribute__((ext_vector_type(4)));
typedef unsigned short u16;
typedef u16 u16x8 __attribute__((ext_vector_type(8)));
typedef u16 u16x4 __attribute__((ext_vector_type(4)));

DEV u16 f2bf(float f) {
  union { float f; uint32_t u; } a; a.f = f;
  uint32_t u = a.u + 0x7fffu + ((a.u >> 16) & 1u);
  return (u16)(u >> 16);
}
DEV float b2f(u16 v) {
  union { uint32_t u; float f; } a; a.u = ((uint32_t)v) << 16;
  return a.f;
}

DEV void gload16(const void* g, void* lds) {
  __builtin_amdgcn_global_load_lds((__attribute__((address_space(1))) void*)g,
                                   (__attribute__((address_space(3))) void*)lds,
                                   16, 0, 0);
}

// ---------------- weight convert + transpose: dst[n][k] = bf16(src[k][n]) ----
struct TMat { const float* src; u16* dst; int K; int N; int t0; };
struct TArgs { TMat m[26]; int nmat; };

__global__ __launch_bounds__(256) void transpose_all(TArgs args) {
  __shared__ float tile[64][65];
  const int bid = blockIdx.x;
  int i = 0;
  #pragma unroll 1
  for (int t = 1; t < args.nmat; ++t) if (bid >= args.m[t].t0) i = t;
  const TMat mm = args.m[i];
  const int tid = bid - mm.t0;
  const int ntx = mm.N >> 6;
  const int tx = tid % ntx, ty = tid / ntx;
  const int n0 = tx * 64, k0 = ty * 64;
  const int c = threadIdx.x & 63, r0 = threadIdx.x >> 6;
  #pragma unroll
  for (int s = 0; s < 16; ++s) {
    int r = r0 + s * 4;
    tile[r][c] = mm.src[(size_t)(k0 + r) * mm.N + n0 + c];
  }
  __syncthreads();
  #pragma unroll
  for (int s = 0; s < 16; ++s) {
    int rr = r0 + s * 4;
    mm.dst[(size_t)(n0 + rr) * mm.K + k0 + c] = f2bf(tile[c][rr]);
  }
}

// ---------------- fp32 copy ----------------
__global__ void copy_f4(const float4* __restrict__ in, float4* __restrict__ out, int n) {
  int i = blockIdx.x * blockDim.x + threadIdx.x;
  if (i < n) out[i] = in[i];
}

// ---------------- LayerNorm: fp32 in -> bf16 out, one wave per token --------
__global__ __launch_bounds__(256) void ln_kernel(const float* __restrict__ x,
                                                 const float* __restrict__ sc,
                                                 const float* __restrict__ bi,
                                                 u16* __restrict__ y, int Mtok) {
  const int tok = (blockIdx.x * blockDim.x + threadIdx.x) >> 6;
  const int l = threadIdx.x & 63;
  if (tok >= Mtok) return;
  const float4* row = (const float4*)(x + (size_t)tok * 768);
  float4 a = row[l], b = row[l + 64], cc = row[l + 128];
  float s = a.x + a.y + a.z + a.w + b.x + b.y + b.z + b.w + cc.x + cc.y + cc.z + cc.w;
  float q = a.x*a.x + a.y*a.y + a.z*a.z + a.w*a.w
          + b.x*b.x + b.y*b.y + b.z*b.z + b.w*b.w
          + cc.x*cc.x + cc.y*cc.y + cc.z*cc.z + cc.w*cc.w;
  #pragma unroll
  for (int off = 1; off < 64; off <<= 1) { s += __shfl_xor(s, off); q += __shfl_xor(q, off); }
  const float mean = s * (1.f / 768.f);
  const float var = q * (1.f / 768.f) - mean * mean;
  const float r = rsqrtf(var + 1e-6f);
  u16* yr = y + (size_t)tok * 768;
  #pragma unroll
  for (int p = 0; p < 3; ++p) {
    const int col0 = 4 * (l + 64 * p);
    float4 v = (p == 0) ? a : (p == 1) ? b : cc;
    float4 scv = *(const float4*)(sc + col0);
    float4 biv = *(const float4*)(bi + col0);
    u16x4 o;
    o[0] = f2bf((v.x - mean) * r * scv.x + biv.x);
    o[1] = f2bf((v.y - mean) * r * scv.y + biv.y);
    o[2] = f2bf((v.z - mean) * r * scv.z + biv.z);
    o[3] = f2bf((v.w - mean) * r * scv.w + biv.w);
    *(u16x4*)(yr + col0) = o;
  }
}

// ---------------- bf16 GEMM 256x256, BK=64, 8 waves, 2-phase dbuf ------------
// C[M,N] = A[M,K] @ Bt[N,K]^T  (+epilogue). Split-K via fp32 atomicAdd.
// grid.x = nxb * 32 * nsplit (M=8192 fixed -> 32 row-blocks).
enum { EPI_BF16 = 0, EPI_ATOM = 1, EPI_GELU = 2 };

__global__ __launch_bounds__(512, 2) void gemm256(
    const u16* __restrict__ A, const u16* __restrict__ Bt,
    const float* __restrict__ bias, float* __restrict__ outF, u16* __restrict__ outB,
    int N, int K, int nxb, int nkt, int epi) {
  __shared__ u16 As[2][16384];
  __shared__ u16 Bs[2][16384];
  const int tid = threadIdx.x;
  const int w = tid >> 6, l = tid & 63;

  // XCD-aware bijective swizzle (all grids here are %8 == 0)
  const int nwg = gridDim.x;
  const int flat = blockIdx.x;
  const int wg = (flat & 7) * (nwg >> 3) + (flat >> 3);
  const int bx = wg % nxb;
  const int by = (wg / nxb) & 31;
  const int sk = wg / (nxb << 5);
  const int m0 = by << 8, n0 = bx << 8;
  const int kt0 = sk * nkt;   // K-tile offset (units of 64)

  const int wrow = (w >> 2) << 7;   // 0 / 128
  const int wcol = (w & 3) << 6;    // 0 / 64 / 128 / 192
  const int cl = l & 15, g = l >> 4;

  f32x4 acc[8][4] = {};

  // staging: wave w stages rows [w*32, w*32+32) of both tiles; 4 gload16 each.
  // LDS linear [row][64]; source column pre-swizzled: slot_log = slot_phys ^ (row&7)
  const int lrow = l >> 3;                     // 0..7 within 8-row group
  const int scol = ((l & 7) ^ lrow) << 3;      // swizzled source col (elements)
  const u16* agp = A  + (size_t)(m0 + (w << 5) + lrow) * K + ((size_t)kt0 << 6) + scol;
  const u16* bgp = Bt + (size_t)(n0 + (w << 5) + lrow) * K + ((size_t)kt0 << 6) + scol;
  u16* const asl = &As[0][0] + (w << 11);
  u16* const bsl = &Bs[0][0] + (w << 11);

  // prologue: stage tile 0 into buf 0
  #pragma unroll
  for (int q = 0; q < 4; ++q) {
    gload16(agp + (size_t)(q * 8) * K, asl + (q << 9));
    gload16(bgp + (size_t)(q * 8) * K, bsl + (q << 9));
  }
  __syncthreads();

  const int sw = cl & 7;
  for (int kt = 0; kt < nkt; ++kt) {
    const int cur = kt & 1;
    if (kt + 1 < nkt) {          // issue next-tile stage BEFORE compute
      const int koff = (kt + 1) << 6;
      const int nb = (cur ^ 1) << 14;
      #pragma unroll
      for (int q = 0; q < 4; ++q) {
        gload16(agp + koff + (size_t)(q * 8) * K, asl + nb + (q << 9));
        gload16(bgp + koff + (size_t)(q * 8) * K, bsl + nb + (q << 9));
      }
    }
    const u16* Ab = &As[cur][0];
    const u16* Bb = &Bs[cur][0];
    #pragma unroll
    for (int ks = 0; ks < 2; ++ks) {
      bf16x8 af[8], bfr[4];
      const int ps = (((ks << 2) | g) ^ sw) << 3;   // swizzled slot (elements)
      #pragma unroll
      for (int mt = 0; mt < 8; ++mt)
        af[mt] = *(const bf16x8*)(Ab + ((wrow + mt * 16 + cl) << 6) + ps);
      #pragma unroll
      for (int nt = 0; nt < 4; ++nt)
        bfr[nt] = *(const bf16x8*)(Bb + ((wcol + nt * 16 + cl) << 6) + ps);
      #pragma unroll
      for (int mt = 0; mt < 8; ++mt)
        #pragma unroll
        for (int nt = 0; nt < 4; ++nt)
          acc[mt][nt] = __builtin_amdgcn_mfma_f32_16x16x32_bf16(af[mt], bfr[nt], acc[mt][nt], 0, 0, 0);
    }
    __syncthreads();
  }

  const int rg = g << 2;
  #pragma unroll
  for (int nt = 0; nt < 4; ++nt) {
    const int col = n0 + wcol + nt * 16 + cl;
    const float bb = (bias && kt0 == 0) ? bias[col] : 0.f;
    #pragma unroll
    for (int mt = 0; mt < 8; ++mt) {
      #pragma unroll
      for (int j = 0; j < 4; ++j) {
        const int row = m0 + wrow + mt * 16 + rg + j;
        const size_t idx = (size_t)row * N + col;
        float v = acc[mt][nt][j] + bb;
        if (epi == EPI_ATOM) {
          atomicAdd(outF + idx, v);
        } else if (epi == EPI_GELU) {
          const float e = __expf(-(1.5957691216f * v + 0.0713548163f * v * v * v));
          outB[idx] = f2bf(v / (1.f + e));
        } else {
          outB[idx] = f2bf(v);
        }
      }
    }
  }
}

// ---------------- flash attention (causal + ALiBi) ---------------------------
__global__ __launch_bounds__(256, 2) void attn_kernel(const u16* __restrict__ qkv,
                                                      u16* __restrict__ o) {
  __shared__ u16 Kt[64][72];
  __shared__ u16 Vt[64][72];
  __shared__ u16 P[4][16][72];
  const int qblk = blockIdx.x, h = blockIdx.y, b = blockIdx.z;
  const int tid = threadIdx.x;
  const int w = tid >> 6, l = tid & 63;
  const int cl = l & 15, g = l >> 4;
  const float scale = 0.125f;
  const float slope = (h < 8) ? exp2f(-(float)(h + 1)) : exp2f(-0.5f - (float)(h - 8));
  const int q0 = qblk * 64;
  const size_t rs_ = 2304;
  const size_t bbase = (size_t)b * 1024 * rs_;

  const u16* qp = qkv + bbase + (size_t)(q0 + w * 16 + cl) * rs_ + h * 64 + g * 8;
  bf16x8 qa0 = *(const bf16x8*)qp;
  bf16x8 qa1 = *(const bf16x8*)(qp + 32);

  float m_r[4], l_r[4];
  f32x4 oacc[4];
  #pragma unroll
  for (int j = 0; j < 4; ++j) { m_r[j] = -1e30f; l_r[j] = 0.f; }
  #pragma unroll
  for (int d = 0; d < 4; ++d) oacc[d] = (f32x4){0.f, 0.f, 0.f, 0.f};

  const int ktok = tid >> 2, kc0 = (tid & 3) << 4;
  const int vtok = tid & 63, vd0 = (tid >> 6) << 4;

  const int nkv = qblk + 1;
  for (int kv = 0; kv < nkv; ++kv) {
    const size_t krow = bbase + (size_t)(kv * 64) * rs_;
    __syncthreads();
    {
      const u16* kp = qkv + krow + (size_t)ktok * rs_ + 768 + h * 64 + kc0;
      *(u16x8*)&Kt[ktok][kc0]     = *(const u16x8*)kp;
      *(u16x8*)&Kt[ktok][kc0 + 8] = *(const u16x8*)(kp + 8);
    }
    {
      const u16* vp = qkv + krow + (size_t)vtok * rs_ + 1536 + h * 64 + vd0;
      u16x8 v0 = *(const u16x8*)vp;
      u16x8 v1 = *(const u16x8*)(vp + 8);
      #pragma unroll
      for (int i = 0; i < 8; ++i) { Vt[vd0 + i][vtok] = v0[i]; Vt[vd0 + 8 + i][vtok] = v1[i]; }
    }
    __syncthreads();

    float sc4[4][4];
    #pragma unroll
    for (int nt = 0; nt < 4; ++nt) {
      bf16x8 bk0 = *(const bf16x8*)&Kt[nt * 16 + cl][g * 8];
      bf16x8 bk1 = *(const bf16x8*)&Kt[nt * 16 + cl][32 + g * 8];
      f32x4 s = (f32x4){0.f, 0.f, 0.f, 0.f};
      s = __builtin_amdgcn_mfma_f32_16x16x32_bf16(qa0, bk0, s, 0, 0, 0);
      s = __builtin_amdgcn_mfma_f32_16x16x32_bf16(qa1, bk1, s, 0, 0, 0);
      const int colg = kv * 64 + nt * 16 + cl;
      #pragma unroll
      for (int j = 0; j < 4; ++j) {
        const int rowg = q0 + w * 16 + (g << 2) + j;
        float v = s[j] * scale + slope * (float)colg;
        sc4[nt][j] = (colg <= rowg) ? v : -1e30f;
      }
    }
    float pm[4];
    #pragma unroll
    for (int j = 0; j < 4; ++j)
      pm[j] = fmaxf(fmaxf(sc4[0][j], sc4[1][j]), fmaxf(sc4[2][j], sc4[3][j]));
    #pragma unroll
    for (int off = 1; off < 16; off <<= 1)
      #pragma unroll
      for (int j = 0; j < 4; ++j) pm[j] = fmaxf(pm[j], __shfl_xor(pm[j], off));
    float alpha[4];
    #pragma unroll
    for (int j = 0; j < 4; ++j) {
      float mn = fmaxf(m_r[j], pm[j]);
      alpha[j] = __expf(m_r[j] - mn);
      m_r[j] = mn;
    }
    float rsum[4] = {0.f, 0.f, 0.f, 0.f};
    float pv[4][4];
    #pragma unroll
    for (int nt = 0; nt < 4; ++nt)
      #pragma unroll
      for (int j = 0; j < 4; ++j) {
        float p = __expf(sc4[nt][j] - m_r[j]);
        pv[nt][j] = p; rsum[j] += p;
      }
    #pragma unroll
    for (int off = 1; off < 16; off <<= 1)
      #pragma unroll
      for (int j = 0; j < 4; ++j) rsum[j] += __shfl_xor(rsum[j], off);
    #pragma unroll
    for (int j = 0; j < 4; ++j) l_r[j] = l_r[j] * alpha[j] + rsum[j];
    #pragma unroll
    for (int d = 0; d < 4; ++d)
      #pragma unroll
      for (int j = 0; j < 4; ++j) oacc[d][j] *= alpha[j];

    #pragma unroll
    for (int nt = 0; nt < 4; ++nt)
      #pragma unroll
      for (int j = 0; j < 4; ++j)
        P[w][(g << 2) + j][nt * 16 + cl] = f2bf(pv[nt][j]);

    bf16x8 pa0 = *(const bf16x8*)&P[w][cl][g * 8];
    bf16x8 pa1 = *(const bf16x8*)&P[w][cl][32 + g * 8];
    #pragma unroll
    for (int d = 0; d < 4; ++d) {
      bf16x8 bv0 = *(const bf16x8*)&Vt[d * 16 + cl][g * 8];
      bf16x8 bv1 = *(const bf16x8*)&Vt[d * 16 + cl][32 + g * 8];
      oacc[d] = __builtin_amdgcn_mfma_f32_16x16x32_bf16(pa0, bv0, oacc[d], 0, 0, 0);
      oacc[d] = __builtin_amdgcn_mfma_f32_16x16x32_bf16(pa1, bv1, oacc[d], 0, 0, 0);
    }
  }

  float inv[4];
  #pragma unroll
  for (int j = 0; j < 4; ++j) inv[j] = 1.f / l_r[j];
  u16* op = o + ((size_t)b * 1024 + q0 + w * 16) * 768 + h * 64;
  #pragma unroll
  for (int d = 0; d < 4; ++d)
    #pragma unroll
    for (int j = 0; j < 4; ++j)
      op[(size_t)((g << 2) + j) * 768 + d * 16 + cl] = f2bf(oacc[d][j] * inv[j]);
}

// ---------------- action head: out[M,7] = relu(f[M,768]) @ w[768,7] ---------
__global__ __launch_bounds__(256) void head2_kernel(const float* __restrict__ act,
                                                    const float* __restrict__ w,
                                                    float* __restrict__ out, int Mtok) {
  const int tok = (blockIdx.x * blockDim.x + threadIdx.x) >> 6;
  const int l = threadIdx.x & 63;
  if (tok >= Mtok) return;
  float s[7] = {0.f, 0.f, 0.f, 0.f, 0.f, 0.f, 0.f};
  const float* ar = act + (size_t)tok * 768;
  #pragma unroll
  for (int i = 0; i < 12; ++i) {
    const int k = l + i * 64;
    const float a = fmaxf(ar[k], 0.f);
    #pragma unroll
    for (int j = 0; j < 7; ++j) s[j] += a * w[k * 7 + j];
  }
  #pragma unroll
  for (int off = 32; off; off >>= 1)
    #pragma unroll
    for (int j = 0; j < 7; ++j) s[j] += __shfl_down(s[j], off);
  if (l == 0) {
    #pragma unroll
    for (int j = 0; j < 7; ++j) out[(size_t)tok * 7 + j] = s[j];
  }
}

// ---------------- orchestration ---------------------------------------------
extern "C" void kernel_launch(void* const* d_in, const int* in_sizes, int n_in,
                              void* d_out, int out_size, void* d_ws, size_t ws_size,
                              hipStream_t stream) {
  const float* x_in = (const float*)d_in[0];
  const float* ln1s = (const float*)d_in[1];
  const float* ln1b = (const float*)d_in[2];
  const float* wqkv = (const float*)d_in[3];
  const float* bqkv = (const float*)d_in[4];
  const float* wo   = (const float*)d_in[5];
  const float* bo   = (const float*)d_in[6];
  const float* ln2s = (const float*)d_in[7];
  const float* ln2b = (const float*)d_in[8];
  const float* w1   = (const float*)d_in[9];
  const float* w2   = (const float*)d_in[10];
  const float* lnfs = (const float*)d_in[11];
  const float* lnfb = (const float*)d_in[12];
  const float* hw1  = (const float*)d_in[13];
  const float* hb1  = (const float*)d_in[14];
  const float* hw2  = (const float*)d_in[15];
  float* out = (float*)d_out;

  const int Mtok = 8192, E = 768, E3 = 2304, F = 3072, DEPTH = 6;

  char* ws = (char*)d_ws;
  size_t off = 0;
  auto alloc = [&](size_t bytes) -> char* {
    char* p = ws + off; off += (bytes + 255) & ~(size_t)255; return p;
  };
  u16*  wqkvt = (u16*)alloc((size_t)DEPTH * E3 * E * 2);
  u16*  wot   = (u16*)alloc((size_t)DEPTH * E * E * 2);
  u16*  w1t   = (u16*)alloc((size_t)DEPTH * F * E * 2);
  u16*  w2t   = (u16*)alloc((size_t)DEPTH * E * F * 2);
  u16*  hw1t  = (u16*)alloc((size_t)E * E * 2);
  float* xb   = (float*)alloc((size_t)Mtok * E * 4);
  u16*  yb    = (u16*)alloc((size_t)Mtok * E * 2);
  u16*  big   = (u16*)alloc((size_t)Mtok * F * 2);
  float* fbuf = (float*)alloc((size_t)Mtok * E * 4);
  (void)ws_size; (void)in_sizes; (void)n_in; (void)out_size;

  TArgs ta; int nm = 0; int t0 = 0;
  auto add = [&](const float* s, u16* d, int K, int N) {
    ta.m[nm].src = s; ta.m[nm].dst = d; ta.m[nm].K = K; ta.m[nm].N = N; ta.m[nm].t0 = t0;
    t0 += (N / 64) * (K / 64); ++nm;
  };
  for (int i = 0; i < DEPTH; ++i) add(wqkv + (size_t)i * E * E3, wqkvt + (size_t)i * E3 * E, E, E3);
  for (int i = 0; i < DEPTH; ++i) add(wo + (size_t)i * E * E, wot + (size_t)i * E * E, E, E);
  for (int i = 0; i < DEPTH; ++i) add(w1 + (size_t)i * E * F, w1t + (size_t)i * F * E, E, F);
  for (int i = 0; i < DEPTH; ++i) add(w2 + (size_t)i * F * E, w2t + (size_t)i * E * F, F, E);
  add(hw1, hw1t, E, E);
  ta.nmat = nm;
  transpose_all<<<t0, 256, 0, stream>>>(ta);

  copy_f4<<<(Mtok * E / 4 + 255) / 256, 256, 0, stream>>>((const float4*)x_in, (float4*)xb, Mtok * E / 4);

  u16* qkvb = big;
  for (int i = 0; i < DEPTH; ++i) {
    ln_kernel<<<Mtok / 4, 256, 0, stream>>>(xb, ln1s + i * E, ln1b + i * E, yb, Mtok);
    // qkv: [8192,768] @ [768,2304] -> bf16, grid 9*32 = 288
    gemm256<<<9 * 32, 512, 0, stream>>>(yb, wqkvt + (size_t)i * E3 * E, bqkv + (size_t)i * E3,
                                        nullptr, qkvb, E3, E, 9, 12, EPI_BF16);
    attn_kernel<<<dim3(16, 12, 8), 256, 0, stream>>>(qkvb, yb);
    // wo: [8192,768] @ [768,768] -> atomic into xb (resid in place), splitK=2, grid 3*32*2 = 192
    gemm256<<<3 * 32 * 2, 512, 0, stream>>>(yb, wot + (size_t)i * E * E, bo + (size_t)i * E,
                                            xb, nullptr, E, E, 3, 6, EPI_ATOM);
    ln_kernel<<<Mtok / 4, 256, 0, stream>>>(xb, ln2s + i * E, ln2b + i * E, yb, Mtok);
    // w1: [8192,768] @ [768,3072] -> gelu bf16, grid 12*32 = 384
    gemm256<<<12 * 32, 512, 0, stream>>>(yb, w1t + (size_t)i * F * E, nullptr,
                                         nullptr, big, F, E, 12, 12, EPI_GELU);
    // w2: [8192,3072] @ [3072,768] -> atomic into xb, splitK=4, grid 3*32*4 = 384
    gemm256<<<3 * 32 * 4, 512, 0, stream>>>(big, w2t + (size_t)i * E * F, nullptr,
                                            xb, nullptr, E, F, 3, 12, EPI_ATOM);
  }
  ln_kernel<<<Mtok / 4, 256, 0, stream>>>(xb, lnfs, lnfb, yb, Mtok);
  hipMemsetAsync(fbuf, 0, (size_t)Mtok * E * 4, stream);
  // head1: [8192,768] @ [768,768] -> atomic fp32 into fbuf, splitK=2, grid 192
  gemm256<<<3 * 32 * 2, 512, 0, stream>>>(yb, hw1t, hb1, fbuf, nullptr, E, E, 3, 6, EPI_ATOM);
  head2_kernel<<<Mtok / 4, 256, 0, stream>>>(fbuf, hw2, out, Mtok);
}

// Round 4
// 1774.773 us; speedup vs baseline: 1.5317x; 1.5317x over previous
//
#include <hip/hip_runtime.h>
#include <hip/hip_bf16.h>
#include <cstdint>

#define DEV __device__ __forceinline__

typedef __bf16 bf16x8 __attribute__((ext_vector_type(8)));
typedef float f32x4 __attribute__((ext_vector_type(4)));
typedef unsigned short u16;
typedef u16 u16x8 __attribute__((ext_vector_type(8)));
typedef u16 u16x4 __attribute__((ext_vector_type(4)));

DEV u16 f2bf(float f) {
  union { float f; uint32_t u; } a; a.f = f;
  uint32_t u = a.u + 0x7fffu + ((a.u >> 16) & 1u);
  return (u16)(u >> 16);
}
DEV float b2f(u16 v) {
  union { uint32_t u; float f; } a; a.u = ((uint32_t)v) << 16;
  return a.f;
}

DEV void gload16(const void* g, void* lds) {
  __builtin_amdgcn_global_load_lds((__attribute__((address_space(1))) void*)g,
                                   (__attribute__((address_space(3))) void*)lds,
                                   16, 0, 0);
}

// ---------------- weight convert + transpose: dst[n][k] = bf16(src[k][n]) ----
struct TMat { const float* src; u16* dst; int K; int N; int t0; };
struct TArgs { TMat m[26]; int nmat; };

__global__ __launch_bounds__(256) void transpose_all(TArgs args) {
  __shared__ float tile[64][65];
  const int bid = blockIdx.x;
  int i = 0;
  #pragma unroll 1
  for (int t = 1; t < args.nmat; ++t) if (bid >= args.m[t].t0) i = t;
  const TMat mm = args.m[i];
  const int tid = bid - mm.t0;
  const int ntx = mm.N >> 6;
  const int tx = tid % ntx, ty = tid / ntx;
  const int n0 = tx * 64, k0 = ty * 64;
  const int c = threadIdx.x & 63, r0 = threadIdx.x >> 6;
  #pragma unroll
  for (int s = 0; s < 16; ++s) {
    int r = r0 + s * 4;
    tile[r][c] = mm.src[(size_t)(k0 + r) * mm.N + n0 + c];
  }
  __syncthreads();
  #pragma unroll
  for (int s = 0; s < 16; ++s) {
    int rr = r0 + s * 4;
    mm.dst[(size_t)(n0 + rr) * mm.K + k0 + c] = f2bf(tile[c][rr]);
  }
}

// ---------------- fp32 copy ----------------
__global__ void copy_f4(const float4* __restrict__ in, float4* __restrict__ out, int n) {
  int i = blockIdx.x * blockDim.x + threadIdx.x;
  if (i < n) out[i] = in[i];
}

// ---------------- LayerNorm: fp32 in -> bf16 out, one wave per token --------
__global__ __launch_bounds__(256) void ln_kernel(const float* __restrict__ x,
                                                 const float* __restrict__ sc,
                                                 const float* __restrict__ bi,
                                                 u16* __restrict__ y, int Mtok) {
  const int tok = (blockIdx.x * blockDim.x + threadIdx.x) >> 6;
  const int l = threadIdx.x & 63;
  if (tok >= Mtok) return;
  const float4* row = (const float4*)(x + (size_t)tok * 768);
  float4 a = row[l], b = row[l + 64], cc = row[l + 128];
  float s = a.x + a.y + a.z + a.w + b.x + b.y + b.z + b.w + cc.x + cc.y + cc.z + cc.w;
  float q = a.x*a.x + a.y*a.y + a.z*a.z + a.w*a.w
          + b.x*b.x + b.y*b.y + b.z*b.z + b.w*b.w
          + cc.x*cc.x + cc.y*cc.y + cc.z*cc.z + cc.w*cc.w;
  #pragma unroll
  for (int off = 1; off < 64; off <<= 1) { s += __shfl_xor(s, off); q += __shfl_xor(q, off); }
  const float mean = s * (1.f / 768.f);
  const float var = q * (1.f / 768.f) - mean * mean;
  const float r = rsqrtf(var + 1e-6f);
  u16* yr = y + (size_t)tok * 768;
  #pragma unroll
  for (int p = 0; p < 3; ++p) {
    const int col0 = 4 * (l + 64 * p);
    float4 v = (p == 0) ? a : (p == 1) ? b : cc;
    float4 scv = *(const float4*)(sc + col0);
    float4 biv = *(const float4*)(bi + col0);
    u16x4 o;
    o[0] = f2bf((v.x - mean) * r * scv.x + biv.x);
    o[1] = f2bf((v.y - mean) * r * scv.y + biv.y);
    o[2] = f2bf((v.z - mean) * r * scv.z + biv.z);
    o[3] = f2bf((v.w - mean) * r * scv.w + biv.w);
    *(u16x4*)(yr + col0) = o;
  }
}

// ---------------- bf16 GEMM 128x128, BK=64, 4 waves, 2-phase dbuf -----------
// C[M,N] = A[M,K] @ Bt[N,K]^T (+fused epilogue). Coalesced stores via LDS
// transpose. No split-K. 64 KB LDS -> 2 blocks/CU.
enum { EPI_BF16 = 0, EPI_RESID = 1, EPI_GELU = 2, EPI_RELU = 3 };

__global__ __launch_bounds__(256, 2) void gemm128(
    const u16* __restrict__ A, const u16* __restrict__ Bt,
    const float* __restrict__ bias, const float* __restrict__ resid,
    float* __restrict__ outF, u16* __restrict__ outB,
    int N, int K, int nxb, int epi) {
  __shared__ u16 smem[32768];   // As[2][8192] @ 0, Bs[2][8192] @ 16384
  const int tid = threadIdx.x;
  const int w = tid >> 6, l = tid & 63;

  // XCD-aware bijective swizzle (grids here are all %8 == 0)
  const int nwg = gridDim.x;
  const int flat = blockIdx.x;
  const int wg = (flat & 7) * (nwg >> 3) + (flat >> 3);
  const int bx = wg % nxb, by = wg / nxb;
  const int m0 = by << 7, n0 = bx << 7;

  const int wr = (w >> 1) << 6, wc = (w & 1) << 6;
  const int cl = l & 15, g = l >> 4;
  f32x4 acc[4][4] = {};

  // staging: wave w stages A rows [w*32,w*32+32) and B rows same; 8 rows/gload
  const int lrow = l >> 3;                    // 0..7
  const int scol = ((l & 7) ^ lrow) << 3;     // pre-swizzled source col (elems)
  const u16* agp = A  + (size_t)(m0 + (w << 5) + lrow) * K + scol;
  const u16* bgp = Bt + (size_t)(n0 + (w << 5) + lrow) * K + scol;
  const int ldso = w << 11;                   // wave region: 2048 elems
  const int nkt = K >> 6;

  // prologue: stage kt=0 into buf0
  #pragma unroll
  for (int q = 0; q < 4; ++q) {
    gload16(agp + (size_t)(q * 8) * K, &smem[ldso + (q << 9)]);
    gload16(bgp + (size_t)(q * 8) * K, &smem[16384 + ldso + (q << 9)]);
  }
  __syncthreads();

  const int sw = cl & 7;
  for (int kt = 0; kt < nkt; ++kt) {
    const int cur = kt & 1;
    if (kt + 1 < nkt) {                       // prefetch next tile into buf^1
      const size_t koff = (size_t)(kt + 1) << 6;
      const int nb = (cur ^ 1) << 13;
      #pragma unroll
      for (int q = 0; q < 4; ++q) {
        gload16(agp + koff + (size_t)(q * 8) * K, &smem[nb + ldso + (q << 9)]);
        gload16(bgp + koff + (size_t)(q * 8) * K, &smem[16384 + nb + ldso + (q << 9)]);
      }
    }
    const u16* Ab = &smem[cur << 13];
    const u16* Bb = &smem[16384 + (cur << 13)];
    #pragma unroll
    for (int ks = 0; ks < 2; ++ks) {
      bf16x8 af[4], bfr[4];
      const int ps = (((ks << 2) | g) ^ sw) << 3;
      #pragma unroll
      for (int mt = 0; mt < 4; ++mt)
        af[mt] = *(const bf16x8*)(Ab + ((wr + mt * 16 + cl) << 6) + ps);
      #pragma unroll
      for (int nt = 0; nt < 4; ++nt)
        bfr[nt] = *(const bf16x8*)(Bb + ((wc + nt * 16 + cl) << 6) + ps);
      #pragma unroll
      for (int mt = 0; mt < 4; ++mt)
        #pragma unroll
        for (int nt = 0; nt < 4; ++nt)
          acc[mt][nt] = __builtin_amdgcn_mfma_f32_16x16x32_bf16(af[mt], bfr[nt], acc[mt][nt], 0, 0, 0);
    }
    __syncthreads();
  }

  // ---- epilogue: per-wave LDS transpose -> coalesced 16B/32B per-lane stores
  float* scr = (float*)smem + w * 1056;       // 16 x 66 fp32 per wave
  const int rg = g << 2;
  const int er = l >> 3;                      // 0..7
  const int ec0 = (l & 7) << 3;               // 0,8,..,56
  #pragma unroll
  for (int mt = 0; mt < 4; ++mt) {
    #pragma unroll
    for (int nt = 0; nt < 4; ++nt)
      #pragma unroll
      for (int j = 0; j < 4; ++j)
        scr[(rg + j) * 66 + nt * 16 + cl] = acc[mt][nt][j];
    #pragma unroll
    for (int t = 0; t < 2; ++t) {
      const int r = (t << 3) + er;
      const int grow = m0 + wr + mt * 16 + r;
      const int gcol = n0 + wc + ec0;
      float v[8];
      #pragma unroll
      for (int u = 0; u < 8; ++u) v[u] = scr[r * 66 + ec0 + u];
      if (bias) {
        #pragma unroll
        for (int u = 0; u < 8; ++u) v[u] += bias[gcol + u];
      }
      if (epi == EPI_RESID) {
        const float* rp = resid + (size_t)grow * N + gcol;
        float* op = outF + (size_t)grow * N + gcol;
        float4 o0, o1;
        o0.x = v[0] + rp[0]; o0.y = v[1] + rp[1]; o0.z = v[2] + rp[2]; o0.w = v[3] + rp[3];
        o1.x = v[4] + rp[4]; o1.y = v[5] + rp[5]; o1.z = v[6] + rp[6]; o1.w = v[7] + rp[7];
        *(float4*)op = o0;
        *(float4*)(op + 4) = o1;
      } else {
        u16x8 ov;
        #pragma unroll
        for (int u = 0; u < 8; ++u) {
          float x = v[u];
          if (epi == EPI_GELU) {
            const float e = __expf(-(1.5957691216f * x + 0.0713548163f * x * x * x));
            x = x / (1.f + e);
          } else if (epi == EPI_RELU) {
            x = fmaxf(x, 0.f);
          }
          ov[u] = f2bf(x);
        }
        *(u16x8*)(outB + (size_t)grow * N + gcol) = ov;
      }
    }
  }
}

// ---------------- flash attention (causal + ALiBi) ---------------------------
__global__ __launch_bounds__(256, 2) void attn_kernel(const u16* __restrict__ qkv,
                                                      u16* __restrict__ o) {
  __shared__ u16 Kt[64][72];
  __shared__ u16 Vt[64][72];
  __shared__ u16 P[4][16][72];
  const int qblk = blockIdx.x, h = blockIdx.y, b = blockIdx.z;
  const int tid = threadIdx.x;
  const int w = tid >> 6, l = tid & 63;
  const int cl = l & 15, g = l >> 4;
  const float scale = 0.125f;
  const float slope = (h < 8) ? exp2f(-(float)(h + 1)) : exp2f(-0.5f - (float)(h - 8));
  const int q0 = qblk * 64;
  const size_t rs_ = 2304;
  const size_t bbase = (size_t)b * 1024 * rs_;

  const u16* qp = qkv + bbase + (size_t)(q0 + w * 16 + cl) * rs_ + h * 64 + g * 8;
  bf16x8 qa0 = *(const bf16x8*)qp;
  bf16x8 qa1 = *(const bf16x8*)(qp + 32);

  float m_r[4], l_r[4];
  f32x4 oacc[4];
  #pragma unroll
  for (int j = 0; j < 4; ++j) { m_r[j] = -1e30f; l_r[j] = 0.f; }
  #pragma unroll
  for (int d = 0; d < 4; ++d) oacc[d] = (f32x4){0.f, 0.f, 0.f, 0.f};

  const int ktok = tid >> 2, kc0 = (tid & 3) << 4;
  const int vtok = tid & 63, vd0 = (tid >> 6) << 4;

  const int nkv = qblk + 1;
  for (int kv = 0; kv < nkv; ++kv) {
    const size_t krow = bbase + (size_t)(kv * 64) * rs_;
    __syncthreads();
    {
      const u16* kp = qkv + krow + (size_t)ktok * rs_ + 768 + h * 64 + kc0;
      *(u16x8*)&Kt[ktok][kc0]     = *(const u16x8*)kp;
      *(u16x8*)&Kt[ktok][kc0 + 8] = *(const u16x8*)(kp + 8);
    }
    {
      const u16* vp = qkv + krow + (size_t)vtok * rs_ + 1536 + h * 64 + vd0;
      u16x8 v0 = *(const u16x8*)vp;
      u16x8 v1 = *(const u16x8*)(vp + 8);
      #pragma unroll
      for (int i = 0; i < 8; ++i) { Vt[vd0 + i][vtok] = v0[i]; Vt[vd0 + 8 + i][vtok] = v1[i]; }
    }
    __syncthreads();

    float sc4[4][4];
    #pragma unroll
    for (int nt = 0; nt < 4; ++nt) {
      bf16x8 bk0 = *(const bf16x8*)&Kt[nt * 16 + cl][g * 8];
      bf16x8 bk1 = *(const bf16x8*)&Kt[nt * 16 + cl][32 + g * 8];
      f32x4 s = (f32x4){0.f, 0.f, 0.f, 0.f};
      s = __builtin_amdgcn_mfma_f32_16x16x32_bf16(qa0, bk0, s, 0, 0, 0);
      s = __builtin_amdgcn_mfma_f32_16x16x32_bf16(qa1, bk1, s, 0, 0, 0);
      const int colg = kv * 64 + nt * 16 + cl;
      #pragma unroll
      for (int j = 0; j < 4; ++j) {
        const int rowg = q0 + w * 16 + (g << 2) + j;
        float v = s[j] * scale + slope * (float)colg;
        sc4[nt][j] = (colg <= rowg) ? v : -1e30f;
      }
    }
    float pm[4];
    #pragma unroll
    for (int j = 0; j < 4; ++j)
      pm[j] = fmaxf(fmaxf(sc4[0][j], sc4[1][j]), fmaxf(sc4[2][j], sc4[3][j]));
    #pragma unroll
    for (int off = 1; off < 16; off <<= 1)
      #pragma unroll
      for (int j = 0; j < 4; ++j) pm[j] = fmaxf(pm[j], __shfl_xor(pm[j], off));
    float alpha[4];
    #pragma unroll
    for (int j = 0; j < 4; ++j) {
      float mn = fmaxf(m_r[j], pm[j]);
      alpha[j] = __expf(m_r[j] - mn);
      m_r[j] = mn;
    }
    float rsum[4] = {0.f, 0.f, 0.f, 0.f};
    float pv[4][4];
    #pragma unroll
    for (int nt = 0; nt < 4; ++nt)
      #pragma unroll
      for (int j = 0; j < 4; ++j) {
        float p = __expf(sc4[nt][j] - m_r[j]);
        pv[nt][j] = p; rsum[j] += p;
      }
    #pragma unroll
    for (int off = 1; off < 16; off <<= 1)
      #pragma unroll
      for (int j = 0; j < 4; ++j) rsum[j] += __shfl_xor(rsum[j], off);
    #pragma unroll
    for (int j = 0; j < 4; ++j) l_r[j] = l_r[j] * alpha[j] + rsum[j];
    #pragma unroll
    for (int d = 0; d < 4; ++d)
      #pragma unroll
      for (int j = 0; j < 4; ++j) oacc[d][j] *= alpha[j];

    #pragma unroll
    for (int nt = 0; nt < 4; ++nt)
      #pragma unroll
      for (int j = 0; j < 4; ++j)
        P[w][(g << 2) + j][nt * 16 + cl] = f2bf(pv[nt][j]);

    bf16x8 pa0 = *(const bf16x8*)&P[w][cl][g * 8];
    bf16x8 pa1 = *(const bf16x8*)&P[w][cl][32 + g * 8];
    #pragma unroll
    for (int d = 0; d < 4; ++d) {
      bf16x8 bv0 = *(const bf16x8*)&Vt[d * 16 + cl][g * 8];
      bf16x8 bv1 = *(const bf16x8*)&Vt[d * 16 + cl][32 + g * 8];
      oacc[d] = __builtin_amdgcn_mfma_f32_16x16x32_bf16(pa0, bv0, oacc[d], 0, 0, 0);
      oacc[d] = __builtin_amdgcn_mfma_f32_16x16x32_bf16(pa1, bv1, oacc[d], 0, 0, 0);
    }
  }

  float inv[4];
  #pragma unroll
  for (int j = 0; j < 4; ++j) inv[j] = 1.f / l_r[j];
  u16* op = o + ((size_t)b * 1024 + q0 + w * 16) * 768 + h * 64;
  #pragma unroll
  for (int d = 0; d < 4; ++d)
    #pragma unroll
    for (int j = 0; j < 4; ++j)
      op[(size_t)((g << 2) + j) * 768 + d * 16 + cl] = f2bf(oacc[d][j] * inv[j]);
}

// ---------------- action head: out[M,7] = act[M,768] @ w[768,7] --------------
__global__ __launch_bounds__(256) void head2_kernel(const u16* __restrict__ act,
                                                    const float* __restrict__ w,
                                                    float* __restrict__ out, int Mtok) {
  const int tok = (blockIdx.x * blockDim.x + threadIdx.x) >> 6;
  const int l = threadIdx.x & 63;
  if (tok >= Mtok) return;
  float s[7] = {0.f, 0.f, 0.f, 0.f, 0.f, 0.f, 0.f};
  const u16* ar = act + (size_t)tok * 768;
  #pragma unroll
  for (int i = 0; i < 12; ++i) {
    const int k = l + i * 64;
    const float a = b2f(ar[k]);
    #pragma unroll
    for (int j = 0; j < 7; ++j) s[j] += a * w[k * 7 + j];
  }
  #pragma unroll
  for (int off = 32; off; off >>= 1)
    #pragma unroll
    for (int j = 0; j < 7; ++j) s[j] += __shfl_down(s[j], off);
  if (l == 0) {
    #pragma unroll
    for (int j = 0; j < 7; ++j) out[(size_t)tok * 7 + j] = s[j];
  }
}

// ---------------- orchestration ---------------------------------------------
extern "C" void kernel_launch(void* const* d_in, const int* in_sizes, int n_in,
                              void* d_out, int out_size, void* d_ws, size_t ws_size,
                              hipStream_t stream) {
  const float* x_in = (const float*)d_in[0];
  const float* ln1s = (const float*)d_in[1];
  const float* ln1b = (const float*)d_in[2];
  const float* wqkv = (const float*)d_in[3];
  const float* bqkv = (const float*)d_in[4];
  const float* wo   = (const float*)d_in[5];
  const float* bo   = (const float*)d_in[6];
  const float* ln2s = (const float*)d_in[7];
  const float* ln2b = (const float*)d_in[8];
  const float* w1   = (const float*)d_in[9];
  const float* w2   = (const float*)d_in[10];
  const float* lnfs = (const float*)d_in[11];
  const float* lnfb = (const float*)d_in[12];
  const float* hw1  = (const float*)d_in[13];
  const float* hb1  = (const float*)d_in[14];
  const float* hw2  = (const float*)d_in[15];
  float* out = (float*)d_out;

  const int Mtok = 8192, E = 768, E3 = 2304, F = 3072, DEPTH = 6;

  char* ws = (char*)d_ws;
  size_t off = 0;
  auto alloc = [&](size_t bytes) -> char* {
    char* p = ws + off; off += (bytes + 255) & ~(size_t)255; return p;
  };
  u16*  wqkvt = (u16*)alloc((size_t)DEPTH * E3 * E * 2);
  u16*  wot   = (u16*)alloc((size_t)DEPTH * E * E * 2);
  u16*  w1t   = (u16*)alloc((size_t)DEPTH * F * E * 2);
  u16*  w2t   = (u16*)alloc((size_t)DEPTH * E * F * 2);
  u16*  hw1t  = (u16*)alloc((size_t)E * E * 2);
  float* xb   = (float*)alloc((size_t)Mtok * E * 4);
  u16*  yb    = (u16*)alloc((size_t)Mtok * E * 2);
  u16*  big   = (u16*)alloc((size_t)Mtok * F * 2);
  (void)ws_size; (void)in_sizes; (void)n_in; (void)out_size;

  TArgs ta; int nm = 0; int t0 = 0;
  auto add = [&](const float* s, u16* d, int K, int N) {
    ta.m[nm].src = s; ta.m[nm].dst = d; ta.m[nm].K = K; ta.m[nm].N = N; ta.m[nm].t0 = t0;
    t0 += (N / 64) * (K / 64); ++nm;
  };
  for (int i = 0; i < DEPTH; ++i) add(wqkv + (size_t)i * E * E3, wqkvt + (size_t)i * E3 * E, E, E3);
  for (int i = 0; i < DEPTH; ++i) add(wo + (size_t)i * E * E, wot + (size_t)i * E * E, E, E);
  for (int i = 0; i < DEPTH; ++i) add(w1 + (size_t)i * E * F, w1t + (size_t)i * F * E, E, F);
  for (int i = 0; i < DEPTH; ++i) add(w2 + (size_t)i * F * E, w2t + (size_t)i * E * F, F, E);
  add(hw1, hw1t, E, E);
  ta.nmat = nm;
  transpose_all<<<t0, 256, 0, stream>>>(ta);

  copy_f4<<<(Mtok * E / 4 + 255) / 256, 256, 0, stream>>>((const float4*)x_in, (float4*)xb, Mtok * E / 4);

  u16* qkvb = big;
  for (int i = 0; i < DEPTH; ++i) {
    ln_kernel<<<Mtok / 4, 256, 0, stream>>>(xb, ln1s + i * E, ln1b + i * E, yb, Mtok);
    // qkv: grid 18*64 = 1152
    gemm128<<<18 * 64, 256, 0, stream>>>(yb, wqkvt + (size_t)i * E3 * E, bqkv + (size_t)i * E3,
                                         nullptr, nullptr, qkvb, E3, E, 18, EPI_BF16);
    attn_kernel<<<dim3(16, 12, 8), 256, 0, stream>>>(qkvb, yb);
    // wo + resid: grid 6*64 = 384
    gemm128<<<6 * 64, 256, 0, stream>>>(yb, wot + (size_t)i * E * E, bo + (size_t)i * E,
                                        xb, xb, nullptr, E, E, 6, EPI_RESID);
    ln_kernel<<<Mtok / 4, 256, 0, stream>>>(xb, ln2s + i * E, ln2b + i * E, yb, Mtok);
    // w1 + gelu: grid 24*64 = 1536
    gemm128<<<24 * 64, 256, 0, stream>>>(yb, w1t + (size_t)i * F * E, nullptr,
                                         nullptr, nullptr, big, F, E, 24, EPI_GELU);
    // w2 + resid: grid 6*64 = 384 (K=3072)
    gemm128<<<6 * 64, 256, 0, stream>>>(big, w2t + (size_t)i * E * F, nullptr,
                                        xb, xb, nullptr, E, F, 6, EPI_RESID);
  }
  ln_kernel<<<Mtok / 4, 256, 0, stream>>>(xb, lnfs, lnfb, yb, Mtok);
  // head1 + relu -> bf16: grid 384
  gemm128<<<6 * 64, 256, 0, stream>>>(yb, hw1t, hb1, nullptr, nullptr, big,
                                      E, E, 6, EPI_RELU);
  head2_kernel<<<Mtok / 4, 256, 0, stream>>>(big, hw2, out, Mtok);
}

// Round 5
// 1698.084 us; speedup vs baseline: 1.6008x; 1.0452x over previous
//
#include <hip/hip_runtime.h>
#include <hip/hip_bf16.h>
#include <cstdint>

#define DEV __device__ __forceinline__

typedef __bf16 bf16x8 __attribute__((ext_vector_type(8)));
typedef float f32x4 __attribute__((ext_vector_type(4)));
typedef unsigned short u16;
typedef u16 u16x8 __attribute__((ext_vector_type(8)));
typedef u16 u16x4 __attribute__((ext_vector_type(4)));

DEV u16 f2bf(float f) {
  union { float f; uint32_t u; } a; a.f = f;
  uint32_t u = a.u + 0x7fffu + ((a.u >> 16) & 1u);
  return (u16)(u >> 16);
}
DEV float b2f(u16 v) {
  union { uint32_t u; float f; } a; a.u = ((uint32_t)v) << 16;
  return a.f;
}

DEV void gload16(const void* g, void* lds) {
  __builtin_amdgcn_global_load_lds((__attribute__((address_space(1))) void*)g,
                                   (__attribute__((address_space(3))) void*)lds,
                                   16, 0, 0);
}

// ---------------- weight convert + transpose: dst[n][k] = bf16(src[k][n]) ----
struct TMat { const float* src; u16* dst; int K; int N; int t0; };
struct TArgs { TMat m[26]; int nmat; };

__global__ __launch_bounds__(256) void transpose_all(TArgs args) {
  __shared__ float tile[64][65];
  const int bid = blockIdx.x;
  int i = 0;
  #pragma unroll 1
  for (int t = 1; t < args.nmat; ++t) if (bid >= args.m[t].t0) i = t;
  const TMat mm = args.m[i];
  const int tid = bid - mm.t0;
  const int ntx = mm.N >> 6;
  const int tx = tid % ntx, ty = tid / ntx;
  const int n0 = tx * 64, k0 = ty * 64;
  const int c = threadIdx.x & 63, r0 = threadIdx.x >> 6;
  #pragma unroll
  for (int s = 0; s < 16; ++s) {
    int r = r0 + s * 4;
    tile[r][c] = mm.src[(size_t)(k0 + r) * mm.N + n0 + c];
  }
  __syncthreads();
  #pragma unroll
  for (int s = 0; s < 16; ++s) {
    int rr = r0 + s * 4;
    mm.dst[(size_t)(n0 + rr) * mm.K + k0 + c] = f2bf(tile[c][rr]);
  }
}

// ---------------- LayerNorm: fp32 in -> bf16 out, one wave per token --------
__global__ __launch_bounds__(256) void ln_kernel(const float* __restrict__ x,
                                                 const float* __restrict__ sc,
                                                 const float* __restrict__ bi,
                                                 u16* __restrict__ y, int Mtok) {
  const int tok = (blockIdx.x * blockDim.x + threadIdx.x) >> 6;
  const int l = threadIdx.x & 63;
  if (tok >= Mtok) return;
  const float4* row = (const float4*)(x + (size_t)tok * 768);
  float4 a = row[l], b = row[l + 64], cc = row[l + 128];
  float s = a.x + a.y + a.z + a.w + b.x + b.y + b.z + b.w + cc.x + cc.y + cc.z + cc.w;
  float q = a.x*a.x + a.y*a.y + a.z*a.z + a.w*a.w
          + b.x*b.x + b.y*b.y + b.z*b.z + b.w*b.w
          + cc.x*cc.x + cc.y*cc.y + cc.z*cc.z + cc.w*cc.w;
  #pragma unroll
  for (int off = 1; off < 64; off <<= 1) { s += __shfl_xor(s, off); q += __shfl_xor(q, off); }
  const float mean = s * (1.f / 768.f);
  const float var = q * (1.f / 768.f) - mean * mean;
  const float r = rsqrtf(var + 1e-6f);
  u16* yr = y + (size_t)tok * 768;
  #pragma unroll
  for (int p = 0; p < 3; ++p) {
    const int col0 = 4 * (l + 64 * p);
    float4 v = (p == 0) ? a : (p == 1) ? b : cc;
    float4 scv = *(const float4*)(sc + col0);
    float4 biv = *(const float4*)(bi + col0);
    u16x4 o;
    o[0] = f2bf((v.x - mean) * r * scv.x + biv.x);
    o[1] = f2bf((v.y - mean) * r * scv.y + biv.y);
    o[2] = f2bf((v.z - mean) * r * scv.z + biv.z);
    o[3] = f2bf((v.w - mean) * r * scv.w + biv.w);
    *(u16x4*)(yr + col0) = o;
  }
}

// ---------------- bf16 GEMM 128x128, BK=64, 4 waves, 2-phase dbuf -----------
enum { EPI_BF16 = 0, EPI_RESID = 1, EPI_GELU = 2, EPI_RELU = 3 };

__global__ __launch_bounds__(256, 2) void gemm128(
    const u16* __restrict__ A, const u16* __restrict__ Bt,
    const float* __restrict__ bias, const float* __restrict__ resid,
    float* __restrict__ outF, u16* __restrict__ outB,
    int N, int K, int nxb, int epi) {
  __shared__ u16 smem[32768];   // As[2][8192] @ 0, Bs[2][8192] @ 16384
  const int tid = threadIdx.x;
  const int w = tid >> 6, l = tid & 63;

  const int nwg = gridDim.x;
  const int flat = blockIdx.x;
  const int wg = (flat & 7) * (nwg >> 3) + (flat >> 3);
  const int bx = wg % nxb, by = wg / nxb;
  const int m0 = by << 7, n0 = bx << 7;

  const int wr = (w >> 1) << 6, wc = (w & 1) << 6;
  const int cl = l & 15, g = l >> 4;
  f32x4 acc[4][4] = {};

  const int lrow = l >> 3;
  const int scol = ((l & 7) ^ lrow) << 3;
  const u16* agp = A  + (size_t)(m0 + (w << 5) + lrow) * K + scol;
  const u16* bgp = Bt + (size_t)(n0 + (w << 5) + lrow) * K + scol;
  const int ldso = w << 11;
  const int nkt = K >> 6;

  #pragma unroll
  for (int q = 0; q < 4; ++q) {
    gload16(agp + (size_t)(q * 8) * K, &smem[ldso + (q << 9)]);
    gload16(bgp + (size_t)(q * 8) * K, &smem[16384 + ldso + (q << 9)]);
  }
  __syncthreads();

  const int sw = cl & 7;
  for (int kt = 0; kt < nkt; ++kt) {
    const int cur = kt & 1;
    if (kt + 1 < nkt) {
      const size_t koff = (size_t)(kt + 1) << 6;
      const int nb = (cur ^ 1) << 13;
      #pragma unroll
      for (int q = 0; q < 4; ++q) {
        gload16(agp + koff + (size_t)(q * 8) * K, &smem[nb + ldso + (q << 9)]);
        gload16(bgp + koff + (size_t)(q * 8) * K, &smem[16384 + nb + ldso + (q << 9)]);
      }
    }
    const u16* Ab = &smem[cur << 13];
    const u16* Bb = &smem[16384 + (cur << 13)];
    #pragma unroll
    for (int ks = 0; ks < 2; ++ks) {
      bf16x8 af[4], bfr[4];
      const int ps = (((ks << 2) | g) ^ sw) << 3;
      #pragma unroll
      for (int mt = 0; mt < 4; ++mt)
        af[mt] = *(const bf16x8*)(Ab + ((wr + mt * 16 + cl) << 6) + ps);
      #pragma unroll
      for (int nt = 0; nt < 4; ++nt)
        bfr[nt] = *(const bf16x8*)(Bb + ((wc + nt * 16 + cl) << 6) + ps);
      #pragma unroll
      for (int mt = 0; mt < 4; ++mt)
        #pragma unroll
        for (int nt = 0; nt < 4; ++nt)
          acc[mt][nt] = __builtin_amdgcn_mfma_f32_16x16x32_bf16(af[mt], bfr[nt], acc[mt][nt], 0, 0, 0);
    }
    __syncthreads();
  }

  // epilogue: per-wave LDS transpose -> coalesced stores
  float* scr = (float*)smem + w * 1056;
  const int rg = g << 2;
  const int er = l >> 3;
  const int ec0 = (l & 7) << 3;
  #pragma unroll
  for (int mt = 0; mt < 4; ++mt) {
    #pragma unroll
    for (int nt = 0; nt < 4; ++nt)
      #pragma unroll
      for (int j = 0; j < 4; ++j)
        scr[(rg + j) * 66 + nt * 16 + cl] = acc[mt][nt][j];
    #pragma unroll
    for (int t = 0; t < 2; ++t) {
      const int r = (t << 3) + er;
      const int grow = m0 + wr + mt * 16 + r;
      const int gcol = n0 + wc + ec0;
      float v[8];
      #pragma unroll
      for (int u = 0; u < 8; ++u) v[u] = scr[r * 66 + ec0 + u];
      if (bias) {
        #pragma unroll
        for (int u = 0; u < 8; ++u) v[u] += bias[gcol + u];
      }
      if (epi == EPI_RESID) {
        const float* rp = resid + (size_t)grow * N + gcol;
        float* op = outF + (size_t)grow * N + gcol;
        float4 o0, o1;
        o0.x = v[0] + rp[0]; o0.y = v[1] + rp[1]; o0.z = v[2] + rp[2]; o0.w = v[3] + rp[3];
        o1.x = v[4] + rp[4]; o1.y = v[5] + rp[5]; o1.z = v[6] + rp[6]; o1.w = v[7] + rp[7];
        *(float4*)op = o0;
        *(float4*)(op + 4) = o1;
      } else {
        u16x8 ov;
        #pragma unroll
        for (int u = 0; u < 8; ++u) {
          float x = v[u];
          if (epi == EPI_GELU) {
            const float e = __expf(-(1.5957691216f * x + 0.0713548163f * x * x * x));
            x = x / (1.f + e);
          } else if (epi == EPI_RELU) {
            x = fmaxf(x, 0.f);
          }
          ov[u] = f2bf(x);
        }
        *(u16x8*)(outB + (size_t)grow * N + gcol) = ov;
      }
    }
  }
}

// ---------------- flash attention (causal + ALiBi), XCD-chunked --------------
// grid = 768 1-D: b = flat&7 (XCD chunk), h = (flat>>3)>>3, qgroup = 7-(flat>>3&7).
// QBLK = 128, 8 waves x 16 q-rows; KV tiles of 64.
__global__ __launch_bounds__(512, 2) void attn_kernel(const u16* __restrict__ qkv,
                                                      u16* __restrict__ o) {
  __shared__ u16 Kt[64][72];
  __shared__ u16 Vt[64][72];
  __shared__ u16 P[8][16][72];
  const int flat = blockIdx.x;
  const int b = flat & 7;
  const int r = flat >> 3;
  const int h = r >> 3;
  const int qg = 7 - (r & 7);
  const int tid = threadIdx.x;
  const int w = tid >> 6, l = tid & 63;
  const int cl = l & 15, lg = l >> 4;
  const float scale = 0.125f;
  const float slope = (h < 8) ? exp2f(-(float)(h + 1)) : exp2f(-0.5f - (float)(h - 8));
  const int q0 = qg * 128;
  const size_t rs_ = 2304;
  const size_t bbase = (size_t)b * 1024 * rs_;

  const u16* qp = qkv + bbase + (size_t)(q0 + w * 16 + cl) * rs_ + h * 64 + lg * 8;
  bf16x8 qa0 = *(const bf16x8*)qp;
  bf16x8 qa1 = *(const bf16x8*)(qp + 32);

  float m_r[4], l_r[4];
  f32x4 oacc[4];
  #pragma unroll
  for (int j = 0; j < 4; ++j) { m_r[j] = -1e30f; l_r[j] = 0.f; }
  #pragma unroll
  for (int d = 0; d < 4; ++d) oacc[d] = (f32x4){0.f, 0.f, 0.f, 0.f};

  const int ktok = tid >> 3, kc0 = (tid & 7) << 3;   // K: 1x16B per lane
  const int vtok = tid & 63, vd0 = (tid >> 6) << 3;  // V: 8 d-rows per wave

  const int nkv = 2 * qg + 2;
  for (int kv = 0; kv < nkv; ++kv) {
    const size_t krow = bbase + (size_t)(kv * 64) * rs_;
    __syncthreads();
    *(u16x8*)&Kt[ktok][kc0] =
        *(const u16x8*)(qkv + krow + (size_t)ktok * rs_ + 768 + h * 64 + kc0);
    {
      const u16* vp = qkv + krow + (size_t)vtok * rs_ + 1536 + h * 64 + vd0;
      u16x8 v0 = *(const u16x8*)vp;
      #pragma unroll
      for (int i = 0; i < 8; ++i) Vt[vd0 + i][vtok] = v0[i];
    }
    __syncthreads();

    float sc4[4][4];
    #pragma unroll
    for (int nt = 0; nt < 4; ++nt) {
      bf16x8 bk0 = *(const bf16x8*)&Kt[nt * 16 + cl][lg * 8];
      bf16x8 bk1 = *(const bf16x8*)&Kt[nt * 16 + cl][32 + lg * 8];
      f32x4 s = (f32x4){0.f, 0.f, 0.f, 0.f};
      s = __builtin_amdgcn_mfma_f32_16x16x32_bf16(qa0, bk0, s, 0, 0, 0);
      s = __builtin_amdgcn_mfma_f32_16x16x32_bf16(qa1, bk1, s, 0, 0, 0);
      const int colg = kv * 64 + nt * 16 + cl;
      #pragma unroll
      for (int j = 0; j < 4; ++j) {
        const int rowg = q0 + w * 16 + (lg << 2) + j;
        float v = s[j] * scale + slope * (float)colg;
        sc4[nt][j] = (colg <= rowg) ? v : -1e30f;
      }
    }
    float pm[4];
    #pragma unroll
    for (int j = 0; j < 4; ++j)
      pm[j] = fmaxf(fmaxf(sc4[0][j], sc4[1][j]), fmaxf(sc4[2][j], sc4[3][j]));
    #pragma unroll
    for (int off = 1; off < 16; off <<= 1)
      #pragma unroll
      for (int j = 0; j < 4; ++j) pm[j] = fmaxf(pm[j], __shfl_xor(pm[j], off));
    float alpha[4];
    #pragma unroll
    for (int j = 0; j < 4; ++j) {
      float mn = fmaxf(m_r[j], pm[j]);
      alpha[j] = __expf(m_r[j] - mn);
      m_r[j] = mn;
    }
    float rsum[4] = {0.f, 0.f, 0.f, 0.f};
    float pv[4][4];
    #pragma unroll
    for (int nt = 0; nt < 4; ++nt)
      #pragma unroll
      for (int j = 0; j < 4; ++j) {
        float p = __expf(sc4[nt][j] - m_r[j]);
        pv[nt][j] = p; rsum[j] += p;
      }
    #pragma unroll
    for (int off = 1; off < 16; off <<= 1)
      #pragma unroll
      for (int j = 0; j < 4; ++j) rsum[j] += __shfl_xor(rsum[j], off);
    #pragma unroll
    for (int j = 0; j < 4; ++j) l_r[j] = l_r[j] * alpha[j] + rsum[j];
    #pragma unroll
    for (int d = 0; d < 4; ++d)
      #pragma unroll
      for (int j = 0; j < 4; ++j) oacc[d][j] *= alpha[j];

    #pragma unroll
    for (int nt = 0; nt < 4; ++nt)
      #pragma unroll
      for (int j = 0; j < 4; ++j)
        P[w][(lg << 2) + j][nt * 16 + cl] = f2bf(pv[nt][j]);

    bf16x8 pa0 = *(const bf16x8*)&P[w][cl][lg * 8];
    bf16x8 pa1 = *(const bf16x8*)&P[w][cl][32 + lg * 8];
    #pragma unroll
    for (int d = 0; d < 4; ++d) {
      bf16x8 bv0 = *(const bf16x8*)&Vt[d * 16 + cl][lg * 8];
      bf16x8 bv1 = *(const bf16x8*)&Vt[d * 16 + cl][32 + lg * 8];
      oacc[d] = __builtin_amdgcn_mfma_f32_16x16x32_bf16(pa0, bv0, oacc[d], 0, 0, 0);
      oacc[d] = __builtin_amdgcn_mfma_f32_16x16x32_bf16(pa1, bv1, oacc[d], 0, 0, 0);
    }
  }

  float inv[4];
  #pragma unroll
  for (int j = 0; j < 4; ++j) inv[j] = 1.f / l_r[j];
  u16* op = o + ((size_t)b * 1024 + q0 + w * 16) * 768 + h * 64;
  #pragma unroll
  for (int d = 0; d < 4; ++d)
    #pragma unroll
    for (int j = 0; j < 4; ++j)
      op[(size_t)((lg << 2) + j) * 768 + d * 16 + cl] = f2bf(oacc[d][j] * inv[j]);
}

// ---------------- action head: out[M,7] = act[M,768] @ w[768,7] --------------
__global__ __launch_bounds__(256) void head2_kernel(const u16* __restrict__ act,
                                                    const float* __restrict__ w,
                                                    float* __restrict__ out, int Mtok) {
  const int tok = (blockIdx.x * blockDim.x + threadIdx.x) >> 6;
  const int l = threadIdx.x & 63;
  if (tok >= Mtok) return;
  float s[7] = {0.f, 0.f, 0.f, 0.f, 0.f, 0.f, 0.f};
  const u16* ar = act + (size_t)tok * 768;
  #pragma unroll
  for (int i = 0; i < 12; ++i) {
    const int k = l + i * 64;
    const float a = b2f(ar[k]);
    #pragma unroll
    for (int j = 0; j < 7; ++j) s[j] += a * w[k * 7 + j];
  }
  #pragma unroll
  for (int off = 32; off; off >>= 1)
    #pragma unroll
    for (int j = 0; j < 7; ++j) s[j] += __shfl_down(s[j], off);
  if (l == 0) {
    #pragma unroll
    for (int j = 0; j < 7; ++j) out[(size_t)tok * 7 + j] = s[j];
  }
}

// ---------------- orchestration ---------------------------------------------
extern "C" void kernel_launch(void* const* d_in, const int* in_sizes, int n_in,
                              void* d_out, int out_size, void* d_ws, size_t ws_size,
                              hipStream_t stream) {
  const float* x_in = (const float*)d_in[0];
  const float* ln1s = (const float*)d_in[1];
  const float* ln1b = (const float*)d_in[2];
  const float* wqkv = (const float*)d_in[3];
  const float* bqkv = (const float*)d_in[4];
  const float* wo   = (const float*)d_in[5];
  const float* bo   = (const float*)d_in[6];
  const float* ln2s = (const float*)d_in[7];
  const float* ln2b = (const float*)d_in[8];
  const float* w1   = (const float*)d_in[9];
  const float* w2   = (const float*)d_in[10];
  const float* lnfs = (const float*)d_in[11];
  const float* lnfb = (const float*)d_in[12];
  const float* hw1  = (const float*)d_in[13];
  const float* hb1  = (const float*)d_in[14];
  const float* hw2  = (const float*)d_in[15];
  float* out = (float*)d_out;

  const int Mtok = 8192, E = 768, E3 = 2304, F = 3072, DEPTH = 6;

  char* ws = (char*)d_ws;
  size_t off = 0;
  auto alloc = [&](size_t bytes) -> char* {
    char* p = ws + off; off += (bytes + 255) & ~(size_t)255; return p;
  };
  u16*  wqkvt = (u16*)alloc((size_t)DEPTH * E3 * E * 2);
  u16*  wot   = (u16*)alloc((size_t)DEPTH * E * E * 2);
  u16*  w1t   = (u16*)alloc((size_t)DEPTH * F * E * 2);
  u16*  w2t   = (u16*)alloc((size_t)DEPTH * E * F * 2);
  u16*  hw1t  = (u16*)alloc((size_t)E * E * 2);
  float* xb   = (float*)alloc((size_t)Mtok * E * 4);
  u16*  yb    = (u16*)alloc((size_t)Mtok * E * 2);
  u16*  big   = (u16*)alloc((size_t)Mtok * F * 2);
  (void)ws_size; (void)in_sizes; (void)n_in; (void)out_size;

  TArgs ta; int nm = 0; int t0 = 0;
  auto add = [&](const float* s, u16* d, int K, int N) {
    ta.m[nm].src = s; ta.m[nm].dst = d; ta.m[nm].K = K; ta.m[nm].N = N; ta.m[nm].t0 = t0;
    t0 += (N / 64) * (K / 64); ++nm;
  };
  for (int i = 0; i < DEPTH; ++i) add(wqkv + (size_t)i * E * E3, wqkvt + (size_t)i * E3 * E, E, E3);
  for (int i = 0; i < DEPTH; ++i) add(wo + (size_t)i * E * E, wot + (size_t)i * E * E, E, E);
  for (int i = 0; i < DEPTH; ++i) add(w1 + (size_t)i * E * F, w1t + (size_t)i * F * E, E, F);
  for (int i = 0; i < DEPTH; ++i) add(w2 + (size_t)i * F * E, w2t + (size_t)i * E * F, F, E);
  add(hw1, hw1t, E, E);
  ta.nmat = nm;
  transpose_all<<<t0, 256, 0, stream>>>(ta);

  u16* qkvb = big;
  for (int i = 0; i < DEPTH; ++i) {
    const float* xsrc = (i == 0) ? x_in : xb;
    ln_kernel<<<Mtok / 4, 256, 0, stream>>>(xsrc, ln1s + i * E, ln1b + i * E, yb, Mtok);
    gemm128<<<18 * 64, 256, 0, stream>>>(yb, wqkvt + (size_t)i * E3 * E, bqkv + (size_t)i * E3,
                                         nullptr, nullptr, qkvb, E3, E, 18, EPI_BF16);
    attn_kernel<<<768, 512, 0, stream>>>(qkvb, yb);
    gemm128<<<6 * 64, 256, 0, stream>>>(yb, wot + (size_t)i * E * E, bo + (size_t)i * E,
                                        xsrc, xb, nullptr, E, E, 6, EPI_RESID);
    ln_kernel<<<Mtok / 4, 256, 0, stream>>>(xb, ln2s + i * E, ln2b + i * E, yb, Mtok);
    gemm128<<<24 * 64, 256, 0, stream>>>(yb, w1t + (size_t)i * F * E, nullptr,
                                         nullptr, nullptr, big, F, E, 24, EPI_GELU);
    gemm128<<<6 * 64, 256, 0, stream>>>(big, w2t + (size_t)i * E * F, nullptr,
                                        xb, xb, nullptr, E, F, 6, EPI_RESID);
  }
  ln_kernel<<<Mtok / 4, 256, 0, stream>>>(xb, lnfs, lnfb, yb, Mtok);
  gemm128<<<6 * 64, 256, 0, stream>>>(yb, hw1t, hb1, nullptr, nullptr, big,
                                      E, E, 6, EPI_RELU);
  head2_kernel<<<Mtok / 4, 256, 0, stream>>>(big, hw2, out, Mtok);
}